// Round 7
// baseline (15287.575 us; speedup 1.0000x reference)
//
#include <hip/hip_runtime.h>
#include <hip/hip_fp16.h>

#define T_STEPS 4096
#define HD 512
#define G3HD 1536
#define NCODES 4880
#define NWG 16
#define SENT32 0xFFFFFFFFu

typedef __attribute__((ext_vector_type(2))) float v2f;
typedef unsigned long long u64;
typedef unsigned int u32;

#define AL64(P) __hip_atomic_load((P), __ATOMIC_RELAXED, __HIP_MEMORY_SCOPE_AGENT)

static __device__ inline bool ok64(u64 u) {
  return ((u32)u != SENT32) & ((u32)(u >> 32) != SENT32);
}
static __device__ inline v2f cvt2(u32 u) {
  __half2 h = *(__half2*)&u;
  float2 f = __half22float2(h);
  v2f r; r.x = f.x; r.y = f.y; return r;
}

// ---------------------------------------------------------------------------
// GEMM1: visit[4096][512] = H^T (4096x4880) @ X_emb (4880x512)
// ---------------------------------------------------------------------------
__global__ __launch_bounds__(256) void gemm1_kernel(const float* __restrict__ H,
                                                    const float* __restrict__ X,
                                                    float* __restrict__ C) {
  __shared__ float As[16][68];
  __shared__ float Bs[16][68];
  const int m0 = blockIdx.x * 64;
  const int n0 = blockIdx.y * 64;
  const int tid = threadIdx.x;
  const int lk = tid >> 4;
  const int lm = (tid & 15) << 2;
  const int tm = (tid & 15) << 2;
  const int tn = (tid >> 4) << 2;
  float acc[4][4] = {};
  for (int k0 = 0; k0 < NCODES; k0 += 16) {
    float4 av = *(const float4*)(H + (size_t)(k0 + lk) * T_STEPS + m0 + lm);
    float4 bv = *(const float4*)(X + (size_t)(k0 + lk) * HD + n0 + lm);
    __syncthreads();
    *(float4*)(&As[lk][lm]) = av;
    *(float4*)(&Bs[lk][lm]) = bv;
    __syncthreads();
#pragma unroll
    for (int kk = 0; kk < 16; ++kk) {
      float4 a = *(const float4*)(&As[kk][tm]);
      float4 b = *(const float4*)(&Bs[kk][tn]);
      float ar[4] = {a.x, a.y, a.z, a.w};
      float br[4] = {b.x, b.y, b.z, b.w};
#pragma unroll
      for (int i = 0; i < 4; ++i)
#pragma unroll
        for (int j = 0; j < 4; ++j) acc[i][j] += ar[i] * br[j];
    }
  }
#pragma unroll
  for (int i = 0; i < 4; ++i) {
    float4 o = make_float4(acc[i][0], acc[i][1], acc[i][2], acc[i][3]);
    *(float4*)(C + (size_t)(m0 + tm + i) * HD + n0 + tn) = o;
  }
}

// ---------------------------------------------------------------------------
// GEMM2: gi[4096][1536] = visit (4096x512) @ W_ih^T (512x1536) + b_ih
// ---------------------------------------------------------------------------
__global__ __launch_bounds__(256) void gemm2_kernel(const float* __restrict__ A,
                                                    const float* __restrict__ B,
                                                    const float* __restrict__ bias,
                                                    float* __restrict__ Cout) {
  __shared__ float As[16][68];
  __shared__ float Bs[16][68];
  const int m0 = blockIdx.x * 64;
  const int n0 = blockIdx.y * 64;
  const int tid = threadIdx.x;
  const int lr = tid >> 2;
  const int lkq = (tid & 3) << 2;
  const int tm = (tid & 15) << 2;
  const int tn = (tid >> 4) << 2;
  float acc[4][4] = {};
  for (int k0 = 0; k0 < HD; k0 += 16) {
    float4 av = *(const float4*)(A + (size_t)(m0 + lr) * HD + k0 + lkq);
    float4 bv = *(const float4*)(B + (size_t)(n0 + lr) * HD + k0 + lkq);
    __syncthreads();
    As[lkq + 0][lr] = av.x; As[lkq + 1][lr] = av.y;
    As[lkq + 2][lr] = av.z; As[lkq + 3][lr] = av.w;
    Bs[lkq + 0][lr] = bv.x; Bs[lkq + 1][lr] = bv.y;
    Bs[lkq + 2][lr] = bv.z; Bs[lkq + 3][lr] = bv.w;
    __syncthreads();
#pragma unroll
    for (int kk = 0; kk < 16; ++kk) {
      float4 a = *(const float4*)(&As[kk][tm]);
      float4 b = *(const float4*)(&Bs[kk][tn]);
      float ar[4] = {a.x, a.y, a.z, a.w};
      float br[4] = {b.x, b.y, b.z, b.w};
#pragma unroll
      for (int i = 0; i < 4; ++i)
#pragma unroll
        for (int j = 0; j < 4; ++j) acc[i][j] += ar[i] * br[j];
    }
  }
  const float b0 = bias[n0 + tn + 0];
  const float b1 = bias[n0 + tn + 1];
  const float b2 = bias[n0 + tn + 2];
  const float b3 = bias[n0 + tn + 3];
#pragma unroll
  for (int i = 0; i < 4; ++i) {
    float4 o = make_float4(acc[i][0] + b0, acc[i][1] + b1, acc[i][2] + b2, acc[i][3] + b3);
    *(float4*)(Cout + (size_t)(m0 + tm + i) * G3HD + n0 + tn) = o;
  }
}

// ---------------------------------------------------------------------------
// Persistent GRU scan. XCD-pinned 16-WG team; fp16 data-flow exchange via
// AGENT-scope atomics (the R4-proven primitive); 576 thr/WG:
//   tid 0..63   = dedicated POLLER wave: staggered double-probe AGENT poll of
//                 h[t-1] (2x u64/lane = 8 fp16), cvt to fp32 pairs -> hT2;
//                 issues first probes for step t+1 right after the barrier so
//                 probes fly during everyone's compute.
//   tid 64..575 = 512 COMPUTE threads: rg=(tid-64)>>5 owns output elems
//                 2rg,2rg+1 and their 6 W_hh rows (float2 pairs in regs);
//                 kc=(tid-64)&31 is the 16-wide k-chunk. pk_fma matvec +
//                 shfl_xor allreduce; gate lanes (kc<2) compute gates with
//                 native exp/rcp, pack (j0,j1) to one fp16x2 u32, publish via
//                 relaxed AGENT store. ONE barrier/step; race-freedom by
//                 data flow (poll success requires all stores of t-1).
// Sentinel 0xFFFF per half (-NaN, unreachable from finite math); each u32 is
// written atomically by one lane so a non-sentinel u32 is complete.
// ---------------------------------------------------------------------------
__global__ __launch_bounds__(576, 1) void scan_kernel(const float* __restrict__ gi,
                                                      const float* __restrict__ W_hh,
                                                      const float* __restrict__ b_hh,
                                                      __half* __restrict__ hs16,
                                                      int* __restrict__ ctrl) {
  __shared__ int s_role;
  __shared__ v2f hT2[256];  // h[k] pairs: k=16*kc+2m at hT2[m*32+kc]
  const int tid = threadIdx.x;

  if (tid == 0) {
    int xcd;
    asm volatile("s_getreg_b32 %0, hwreg(HW_REG_XCC_ID)" : "=s"(xcd));
    int role = -1;
    const int slot = atomicAdd(&ctrl[xcd], 1);
    if (slot < NWG) {
      if (slot == NWG - 1) atomicCAS(&ctrl[8], -1, xcd);
      int wnr;
      while ((wnr = __hip_atomic_load(&ctrl[8], __ATOMIC_RELAXED,
                                      __HIP_MEMORY_SCOPE_AGENT)) < 0) {
        __builtin_amdgcn_s_sleep(16);
      }
      if (wnr == xcd) role = slot;
    }
    s_role = role;
  }
  __syncthreads();
  const int g = s_role;
  if (g < 0) return;

  if (tid < 64) {
    // ------------------------- POLLER WAVE -------------------------
    __builtin_amdgcn_s_setprio(2);
    const int ln = tid;
    const u64* hbase = (const u64*)hs16;
    u64 a0 = 0, a1 = 0;  // early probes for the upcoming poll target
    for (int t = 0; t < T_STEPS; ++t) {
      if (t == 0) {
        const v2f z2 = (v2f)(0.f);
#pragma unroll
        for (int i = 0; i < 4; ++i) hT2[(4 * (ln & 1) + i) * 32 + (ln >> 1)] = z2;
      } else {
        const u64* p = hbase + (size_t)(t - 1) * 128 + ln * 2;
        u64 r0 = a0, r1 = a1;
        for (;;) {
          u64 b0 = AL64(p), b1 = AL64(p + 1);          // keep probes in flight
          if (ok64(r0) && ok64(r1)) break;
          r0 = AL64(p); r1 = AL64(p + 1);
          if (ok64(b0) && ok64(b1)) { r0 = b0; r1 = b1; break; }
        }
        const int base = 4 * (ln & 1);
        const int col = ln >> 1;
        hT2[(base + 0) * 32 + col] = cvt2((u32)r0);
        hT2[(base + 1) * 32 + col] = cvt2((u32)(r0 >> 32));
        hT2[(base + 2) * 32 + col] = cvt2((u32)r1);
        hT2[(base + 3) * 32 + col] = cvt2((u32)(r1 >> 32));
      }
      __syncthreads();  // release compute waves on hT2 = h[t-1]
      if (t + 1 < T_STEPS) {
        const u64* pn = hbase + (size_t)t * 128 + ln * 2;
        a0 = AL64(pn);  // first probes issued NOW -> in flight during compute
        a1 = AL64(pn + 1);
      }
    }
    return;
  }

  // ------------------------- COMPUTE THREADS -------------------------
  const int ct = tid - 64;
  const int rg = ct >> 5;   // 0..15: owns local elems j0=2rg, j1=2rg+1
  const int kc = ct & 31;   // k-chunk: 16 k (8 pairs) per lane

  // 6 rows: r=0..2 -> gates r/z/n of j0; r=3..5 -> gates of j1
  v2f w2[6][8];
#pragma unroll
  for (int r = 0; r < 6; ++r) {
    const int jl = 2 * rg + (r >= 3);
    const int grow = (r % 3) * HD + g * 32 + jl;
    const v2f* wv = (const v2f*)(W_hh + (size_t)grow * HD + kc * 16);
#pragma unroll
    for (int m = 0; m < 8; ++m) w2[r][m] = wv[m];
  }

  float bh0 = 0.f, bh1 = 0.f, bh2 = 0.f;
  const int jloc = 2 * rg + kc;  // valid for kc<2
  if (kc < 2) {
    bh0 = b_hh[0 * HD + g * 32 + jloc];
    bh1 = b_hh[1 * HD + g * 32 + jloc];
    bh2 = b_hh[2 * HD + g * 32 + jloc];
  }

  float gir = 0.f, giz = 0.f, gin = 0.f;
  if (kc < 2) {
    const float* gp = gi + g * 32 + jloc;
    gir = gp[0];
    giz = gp[HD];
    gin = gp[2 * HD];
  }

  u32* hs_u32 = (u32*)hs16;

  for (int t = 0; t < T_STEPS; ++t) {
    __syncthreads();  // hT2 = h[t-1] ready

    // prefetch next step's gi (hidden behind matvec)
    float gir_n = gir, giz_n = giz, gin_n = gin;
    if (kc < 2 && t + 1 < T_STEPS) {
      const float* gp = gi + (size_t)(t + 1) * G3HD + g * 32 + jloc;
      gir_n = gp[0];
      giz_n = gp[HD];
      gin_n = gp[2 * HD];
    }

    v2f acc[6];
#pragma unroll
    for (int r = 0; r < 6; ++r) acc[r] = (v2f)(0.f);
#pragma unroll
    for (int m = 0; m < 8; ++m) {
      const v2f hv = hT2[m * 32 + kc];
#pragma unroll
      for (int r = 0; r < 6; ++r) acc[r] = __builtin_elementwise_fma(w2[r][m], hv, acc[r]);
    }
    float s[6];
#pragma unroll
    for (int r = 0; r < 6; ++r) s[r] = acc[r].x + acc[r].y;
#pragma unroll
    for (int mask = 1; mask <= 16; mask <<= 1) {
#pragma unroll
      for (int r = 0; r < 6; ++r) s[r] += __shfl_xor(s[r], mask);
    }

    if (kc < 2) {
      const float sr = ((kc == 0) ? s[0] : s[3]) + bh0;
      const float sz = ((kc == 0) ? s[1] : s[4]) + bh1;
      const float sn = ((kc == 0) ? s[2] : s[5]) + bh2;
      const float r = __builtin_amdgcn_rcpf(1.f + __expf(-(gir + sr)));
      const float z = __builtin_amdgcn_rcpf(1.f + __expf(-(giz + sz)));
      const float y = gin + r * sn;
      const float n = 1.f - 2.f * __builtin_amdgcn_rcpf(__expf(2.f * y) + 1.f);
      const int kg = g * 32 + jloc;
      const float hprev = ((const float*)hT2)[(((kg & 15) >> 1) * 32 + (kg >> 4)) * 2 + (kg & 1)];
      const float hnew = n + z * (hprev - n);
      const float other = __shfl_xor(hnew, 1);  // partner gate lane's value
      if (kc == 0) {
        __half2 hp2 = __floats2half2_rn(hnew, other);  // (j0, j1) packed
        const u32 bits = *(u32*)&hp2;
        __hip_atomic_store(hs_u32 + (size_t)t * 256 + g * 16 + rg, bits,
                           __ATOMIC_RELAXED, __HIP_MEMORY_SCOPE_AGENT);
      }
    }
    gir = gir_n; giz = giz_n; gin = gin_n;
  }
}

// ---------------------------------------------------------------------------
// logits[t] = dot(hs16[t], w_att).  64 WGs x 4 waves; one wave per 16 rows.
// ---------------------------------------------------------------------------
__global__ __launch_bounds__(256) void logits_kernel(const __half* __restrict__ hs16,
                                                     const float* __restrict__ w_att,
                                                     float* __restrict__ logits) {
  const int lane = threadIdx.x & 63;
  const int wv = threadIdx.x >> 6;  // 0..3
  float4 wa0 = *(const float4*)(w_att + lane * 8);
  float4 wa1 = *(const float4*)(w_att + lane * 8 + 4);
  const int t0 = blockIdx.x * 64 + wv * 16;
  for (int i = 0; i < 16; ++i) {
    const int t = t0 + i;
    const __half2* hp = (const __half2*)(hs16 + (size_t)t * HD) + lane * 4;
    float2 f0 = __half22float2(hp[0]);
    float2 f1 = __half22float2(hp[1]);
    float2 f2 = __half22float2(hp[2]);
    float2 f3 = __half22float2(hp[3]);
    float s = f0.x * wa0.x + f0.y * wa0.y + f1.x * wa0.z + f1.y * wa0.w +
              f2.x * wa1.x + f2.y * wa1.y + f3.x * wa1.z + f3.y * wa1.w;
#pragma unroll
    for (int o = 1; o <= 32; o <<= 1) s += __shfl_xor(s, o);
    if (lane == 0) logits[t] = s;
  }
}

// ---------------------------------------------------------------------------
// Softmax over 4096 logits, write alpha; zero out.
// ---------------------------------------------------------------------------
__global__ __launch_bounds__(256) void softmax_kernel(const float* __restrict__ logits,
                                                      float* __restrict__ alpha,
                                                      float* __restrict__ out) {
  __shared__ float tmp[4];
  const int tid = threadIdx.x;
  float l[16];
  float m = -1e30f;
#pragma unroll
  for (int i = 0; i < 16; ++i) {
    l[i] = logits[i * 256 + tid];
    m = fmaxf(m, l[i]);
  }
#pragma unroll
  for (int o = 32; o > 0; o >>= 1) m = fmaxf(m, __shfl_xor(m, o));
  if ((tid & 63) == 0) tmp[tid >> 6] = m;
  __syncthreads();
  m = fmaxf(fmaxf(tmp[0], tmp[1]), fmaxf(tmp[2], tmp[3]));
  __syncthreads();
  float e[16];
  float s = 0.f;
#pragma unroll
  for (int i = 0; i < 16; ++i) {
    e[i] = expf(l[i] - m);
    s += e[i];
  }
#pragma unroll
  for (int o = 32; o > 0; o >>= 1) s += __shfl_xor(s, o);
  if ((tid & 63) == 0) tmp[tid >> 6] = s;
  __syncthreads();
  s = tmp[0] + tmp[1] + tmp[2] + tmp[3];
  const float inv = 1.f / s;
#pragma unroll
  for (int i = 0; i < 16; ++i) alpha[i * 256 + tid] = e[i] * inv;
  out[tid] = 0.f;
  out[256 + tid] = 0.f;
}

// ---------------------------------------------------------------------------
// out[j] = sum_t alpha[t] * hs16[t][j].  128 WGs: 2 j-halves x 64 t-chunks.
// ---------------------------------------------------------------------------
__global__ __launch_bounds__(256) void wsum_kernel(const float* __restrict__ alpha,
                                                   const __half* __restrict__ hs16,
                                                   float* __restrict__ out) {
  const int tid = threadIdx.x;
  const int jblk = (blockIdx.x & 1) * 256;
  const int tc = blockIdx.x >> 1;
  float acc = 0.f;
  for (int tt = 0; tt < 64; ++tt) {
    const int t = tc * 64 + tt;
    acc += alpha[t] * __half2float(hs16[(size_t)t * HD + jblk + tid]);
  }
  atomicAdd(&out[jblk + tid], acc);
}

extern "C" void kernel_launch(void* const* d_in, const int* in_sizes, int n_in,
                              void* d_out, int out_size, void* d_ws, size_t ws_size,
                              hipStream_t stream) {
  const float* H     = (const float*)d_in[0];
  // d_in[1] = TE, unused by the reference
  const float* X_emb = (const float*)d_in[2];
  const float* W_ih  = (const float*)d_in[3];
  const float* W_hh  = (const float*)d_in[4];
  const float* b_ih  = (const float*)d_in[5];
  const float* b_hh  = (const float*)d_in[6];
  const float* w_att = (const float*)d_in[7];
  float* out = (float*)d_out;

  char* ws = (char*)d_ws;
  float*  visit  = (float*)(ws + 0);           //  8 MB: 4096x512
  float*  gi     = (float*)(ws + 8388608);     // 25 MB: 4096x1536
  __half* hs16   = (__half*)(ws + 33554432);   //  4 MB: 4096x512 fp16
  float*  logits = (float*)(ws + 41943040);    // 16 KB: 4096
  float*  alpha  = (float*)(ws + 42205184);    // 16 KB
  int*    ctrl   = (int*)(ws + 42221568);      // [0..7] per-XCD counters, [8] winner

  // sentinel-fill hs16 (0xFFFF per half = -NaN, unreachable from finite math)
  hipMemsetAsync(hs16, 0xFF, (size_t)T_STEPS * HD * sizeof(__half), stream);
  hipMemsetAsync(ctrl, 0, 8 * sizeof(int), stream);
  hipMemsetAsync(ctrl + 8, 0xFF, sizeof(int), stream);  // winner = -1

  gemm1_kernel<<<dim3(64, 8), 256, 0, stream>>>(H, X_emb, visit);
  gemm2_kernel<<<dim3(64, 24), 256, 0, stream>>>(visit, W_ih, b_ih, gi);
  scan_kernel<<<256, 576, 0, stream>>>(gi, W_hh, b_hh, hs16, ctrl);
  logits_kernel<<<64, 256, 0, stream>>>(hs16, w_att, logits);
  softmax_kernel<<<1, 256, 0, stream>>>(logits, alpha, out);
  wsum_kernel<<<128, 256, 0, stream>>>(alpha, hs16, out);
}

// Round 8
// 11975.677 us; speedup vs baseline: 1.2766x; 1.2766x over previous
//
#include <hip/hip_runtime.h>

#define T_STEPS 4096
#define HD 512
#define G3HD 1536
#define NCODES 4880
#define NWG 16
#define SENT 0xFFFFFFFFu

typedef __attribute__((ext_vector_type(2))) float v2f;
typedef unsigned long long u64;
typedef unsigned int u32;

#define AL64(P) __hip_atomic_load((P), __ATOMIC_RELAXED, __HIP_MEMORY_SCOPE_AGENT)

static __device__ inline bool ok64(u64 u) {
  return ((u32)u != SENT) & ((u32)(u >> 32) != SENT);
}

// ---------------------------------------------------------------------------
// GEMM1: visit[4096][512] = H^T (4096x4880) @ X_emb (4880x512)
// ---------------------------------------------------------------------------
__global__ __launch_bounds__(256) void gemm1_kernel(const float* __restrict__ H,
                                                    const float* __restrict__ X,
                                                    float* __restrict__ C) {
  __shared__ float As[16][68];
  __shared__ float Bs[16][68];
  const int m0 = blockIdx.x * 64;
  const int n0 = blockIdx.y * 64;
  const int tid = threadIdx.x;
  const int lk = tid >> 4;
  const int lm = (tid & 15) << 2;
  const int tm = (tid & 15) << 2;
  const int tn = (tid >> 4) << 2;
  float acc[4][4] = {};
  for (int k0 = 0; k0 < NCODES; k0 += 16) {
    float4 av = *(const float4*)(H + (size_t)(k0 + lk) * T_STEPS + m0 + lm);
    float4 bv = *(const float4*)(X + (size_t)(k0 + lk) * HD + n0 + lm);
    __syncthreads();
    *(float4*)(&As[lk][lm]) = av;
    *(float4*)(&Bs[lk][lm]) = bv;
    __syncthreads();
#pragma unroll
    for (int kk = 0; kk < 16; ++kk) {
      float4 a = *(const float4*)(&As[kk][tm]);
      float4 b = *(const float4*)(&Bs[kk][tn]);
      float ar[4] = {a.x, a.y, a.z, a.w};
      float br[4] = {b.x, b.y, b.z, b.w};
#pragma unroll
      for (int i = 0; i < 4; ++i)
#pragma unroll
        for (int j = 0; j < 4; ++j) acc[i][j] += ar[i] * br[j];
    }
  }
#pragma unroll
  for (int i = 0; i < 4; ++i) {
    float4 o = make_float4(acc[i][0], acc[i][1], acc[i][2], acc[i][3]);
    *(float4*)(C + (size_t)(m0 + tm + i) * HD + n0 + tn) = o;
  }
}

// ---------------------------------------------------------------------------
// GEMM2: gi[4096][1536] = visit (4096x512) @ W_ih^T (512x1536) + b_ih
// ---------------------------------------------------------------------------
__global__ __launch_bounds__(256) void gemm2_kernel(const float* __restrict__ A,
                                                    const float* __restrict__ B,
                                                    const float* __restrict__ bias,
                                                    float* __restrict__ Cout) {
  __shared__ float As[16][68];
  __shared__ float Bs[16][68];
  const int m0 = blockIdx.x * 64;
  const int n0 = blockIdx.y * 64;
  const int tid = threadIdx.x;
  const int lr = tid >> 2;
  const int lkq = (tid & 3) << 2;
  const int tm = (tid & 15) << 2;
  const int tn = (tid >> 4) << 2;
  float acc[4][4] = {};
  for (int k0 = 0; k0 < HD; k0 += 16) {
    float4 av = *(const float4*)(A + (size_t)(m0 + lr) * HD + k0 + lkq);
    float4 bv = *(const float4*)(B + (size_t)(n0 + lr) * HD + k0 + lkq);
    __syncthreads();
    As[lkq + 0][lr] = av.x; As[lkq + 1][lr] = av.y;
    As[lkq + 2][lr] = av.z; As[lkq + 3][lr] = av.w;
    Bs[lkq + 0][lr] = bv.x; Bs[lkq + 1][lr] = bv.y;
    Bs[lkq + 2][lr] = bv.z; Bs[lkq + 3][lr] = bv.w;
    __syncthreads();
#pragma unroll
    for (int kk = 0; kk < 16; ++kk) {
      float4 a = *(const float4*)(&As[kk][tm]);
      float4 b = *(const float4*)(&Bs[kk][tn]);
      float ar[4] = {a.x, a.y, a.z, a.w};
      float br[4] = {b.x, b.y, b.z, b.w};
#pragma unroll
      for (int i = 0; i < 4; ++i)
#pragma unroll
        for (int j = 0; j < 4; ++j) acc[i][j] += ar[i] * br[j];
    }
  }
  const float b0 = bias[n0 + tn + 0];
  const float b1 = bias[n0 + tn + 1];
  const float b2 = bias[n0 + tn + 2];
  const float b3 = bias[n0 + tn + 3];
#pragma unroll
  for (int i = 0; i < 4; ++i) {
    float4 o = make_float4(acc[i][0] + b0, acc[i][1] + b1, acc[i][2] + b2, acc[i][3] + b3);
    *(float4*)(Cout + (size_t)(m0 + tm + i) * G3HD + n0 + tn) = o;
  }
}

// ---------------------------------------------------------------------------
// Persistent GRU scan = R4 (proven best: fp32 exchange, relaxed AGENT
// atomics, per-gate-lane dword publish) + ONE change: a dedicated POLLER
// wave. 576 thr/WG:
//   tid 0..63   = poller: starts spinning on h[t] the moment step t's
//                 barrier releases, so probes are in flight during compute;
//                 4x u64 AGENT loads/lane vs sentinel 0xFFFFFFFF (-NaN),
//                 scatter fp32 pairs into hT2.
//   tid 64..575 = 512 compute threads: rg=(tid-64)>>5 owns output elems
//                 2rg,2rg+1 + their 6 W_hh rows (float2 pairs in regs);
//                 kc=(tid-64)&31 = 16-wide k-chunk. pk_fma matvec, shfl_xor
//                 allreduce, gates (native exp/rcp) on kc<2 lanes, publish
//                 via relaxed AGENT dword store (R4-proven).
// ONE barrier/step. Race-free: poll success for h[t] requires every WG's own
// slice stored; stores execute after each wave's whole-wave shfl reduce, so
// all hT2 reads of step t are complete before the poller overwrites hT2.
// ---------------------------------------------------------------------------
__global__ __launch_bounds__(576, 1) void scan_kernel(const float* __restrict__ gi,
                                                      const float* __restrict__ W_hh,
                                                      const float* __restrict__ b_hh,
                                                      float* __restrict__ hs,
                                                      int* __restrict__ ctrl) {
  __shared__ int s_role;
  __shared__ v2f hT2[256];  // h[k] pairs: k=16*kc+2m at hT2[m*32+kc]
  const int tid = threadIdx.x;

  if (tid == 0) {
    int xcd;
    asm volatile("s_getreg_b32 %0, hwreg(HW_REG_XCC_ID)" : "=s"(xcd));
    int role = -1;
    const int slot = atomicAdd(&ctrl[xcd], 1);
    if (slot < NWG) {
      if (slot == NWG - 1) atomicCAS(&ctrl[8], -1, xcd);
      int wnr;
      while ((wnr = __hip_atomic_load(&ctrl[8], __ATOMIC_RELAXED,
                                      __HIP_MEMORY_SCOPE_AGENT)) < 0) {
        __builtin_amdgcn_s_sleep(16);
      }
      if (wnr == xcd) role = slot;
    }
    s_role = role;
  }
  __syncthreads();
  const int g = s_role;
  if (g < 0) return;

  unsigned int* hs_u = (unsigned int*)hs;

  if (tid < 64) {
    // ------------------------- POLLER WAVE -------------------------
    const int ln = tid;
    for (int t = 0; t < T_STEPS; ++t) {
      if (t == 0) {
        const v2f z2 = (v2f)(0.f);
#pragma unroll
        for (int m = 0; m < 4; ++m) hT2[((ln & 1) * 4 + m) * 32 + (ln >> 1)] = z2;
      } else {
        const u64* p = (const u64*)(hs_u + (size_t)(t - 1) * HD) + ln * 4;
        u64 u[4];
        bool ok;
        do {
          ok = true;
#pragma unroll
          for (int m = 0; m < 4; ++m) u[m] = AL64(p + m);
#pragma unroll
          for (int m = 0; m < 4; ++m) ok &= ok64(u[m]);
        } while (!ok);
        const int base = (ln & 1) * 4;  // k = ln*8+2m -> pair (ln&1)*4+m, col ln>>1
        const int col = ln >> 1;
#pragma unroll
        for (int m = 0; m < 4; ++m) {
          v2f pv;
          pv.x = __uint_as_float((u32)u[m]);
          pv.y = __uint_as_float((u32)(u[m] >> 32));
          hT2[(base + m) * 32 + col] = pv;
        }
      }
      __syncthreads();  // release compute waves on hT2 = h[t-1]
      // loop immediately: probes for h[t] start flying during compute
    }
    return;
  }

  // ------------------------- COMPUTE THREADS -------------------------
  const int ct = tid - 64;
  const int rg = ct >> 5;   // 0..15: owns local elems j0=2rg, j1=2rg+1
  const int kc = ct & 31;   // k-chunk: 16 k (8 pairs) per lane

  // 6 rows: r=0..2 -> gates r/z/n of j0; r=3..5 -> gates of j1
  v2f w2[6][8];
#pragma unroll
  for (int r = 0; r < 6; ++r) {
    const int jl = 2 * rg + (r >= 3);
    const int grow = (r % 3) * HD + g * 32 + jl;
    const v2f* wv = (const v2f*)(W_hh + (size_t)grow * HD + kc * 16);
#pragma unroll
    for (int m = 0; m < 8; ++m) w2[r][m] = wv[m];
  }

  float bh0 = 0.f, bh1 = 0.f, bh2 = 0.f;
  const int jloc = 2 * rg + kc;  // valid for kc<2
  if (kc < 2) {
    bh0 = b_hh[0 * HD + g * 32 + jloc];
    bh1 = b_hh[1 * HD + g * 32 + jloc];
    bh2 = b_hh[2 * HD + g * 32 + jloc];
  }

  float gir = 0.f, giz = 0.f, gin = 0.f;
  if (kc < 2) {
    const float* gp = gi + g * 32 + jloc;
    gir = gp[0];
    giz = gp[HD];
    gin = gp[2 * HD];
  }

  for (int t = 0; t < T_STEPS; ++t) {
    __syncthreads();  // hT2 = h[t-1] ready

    // prefetch next step's gi (hidden behind matvec)
    float gir_n = gir, giz_n = giz, gin_n = gin;
    if (kc < 2 && t + 1 < T_STEPS) {
      const float* gp = gi + (size_t)(t + 1) * G3HD + g * 32 + jloc;
      gir_n = gp[0];
      giz_n = gp[HD];
      gin_n = gp[2 * HD];
    }

    v2f acc[6];
#pragma unroll
    for (int r = 0; r < 6; ++r) acc[r] = (v2f)(0.f);
#pragma unroll
    for (int m = 0; m < 8; ++m) {
      const v2f hv = hT2[m * 32 + kc];
#pragma unroll
      for (int r = 0; r < 6; ++r) acc[r] = __builtin_elementwise_fma(w2[r][m], hv, acc[r]);
    }
    float s[6];
#pragma unroll
    for (int r = 0; r < 6; ++r) s[r] = acc[r].x + acc[r].y;
#pragma unroll
    for (int mask = 1; mask <= 16; mask <<= 1) {
#pragma unroll
      for (int r = 0; r < 6; ++r) s[r] += __shfl_xor(s[r], mask);
    }

    if (kc < 2) {
      const float sr = ((kc == 0) ? s[0] : s[3]) + bh0;
      const float sz = ((kc == 0) ? s[1] : s[4]) + bh1;
      const float sn = ((kc == 0) ? s[2] : s[5]) + bh2;
      const float r = __builtin_amdgcn_rcpf(1.f + __expf(-(gir + sr)));
      const float z = __builtin_amdgcn_rcpf(1.f + __expf(-(giz + sz)));
      const float y = gin + r * sn;
      const float n = 1.f - 2.f * __builtin_amdgcn_rcpf(__expf(2.f * y) + 1.f);
      const int kg = g * 32 + jloc;
      const float hprev = ((const float*)hT2)[((kg & 15) >> 1) * 64 + (kg >> 4) * 2 + (kg & 1)];
      const float hnew = n + z * (hprev - n);
      __hip_atomic_store(hs_u + (size_t)t * HD + kg, __float_as_uint(hnew),
                         __ATOMIC_RELAXED, __HIP_MEMORY_SCOPE_AGENT);
    }
    gir = gir_n; giz = giz_n; gin = gin_n;
  }
}

// ---------------------------------------------------------------------------
// logits[t] = dot(hs[t], w_att).  64 WGs x 4 waves; one wave per 16 t-rows.
// ---------------------------------------------------------------------------
__global__ __launch_bounds__(256) void logits_kernel(const float* __restrict__ hs,
                                                     const float* __restrict__ w_att,
                                                     float* __restrict__ logits) {
  const int lane = threadIdx.x & 63;
  const int wv = threadIdx.x >> 6;  // 0..3
  float4 wa0 = *(const float4*)(w_att + lane * 8);
  float4 wa1 = *(const float4*)(w_att + lane * 8 + 4);
  const int t0 = blockIdx.x * 64 + wv * 16;
  for (int i = 0; i < 16; ++i) {
    const int t = t0 + i;
    const float* hp = hs + (size_t)t * HD + lane * 8;
    float4 h0 = *(const float4*)hp;
    float4 h1 = *(const float4*)(hp + 4);
    float s = h0.x * wa0.x + h0.y * wa0.y + h0.z * wa0.z + h0.w * wa0.w +
              h1.x * wa1.x + h1.y * wa1.y + h1.z * wa1.z + h1.w * wa1.w;
#pragma unroll
    for (int o = 1; o <= 32; o <<= 1) s += __shfl_xor(s, o);
    if (lane == 0) logits[t] = s;
  }
}

// ---------------------------------------------------------------------------
// Softmax over 4096 logits, write alpha; zero out.
// ---------------------------------------------------------------------------
__global__ __launch_bounds__(256) void softmax_kernel(const float* __restrict__ logits,
                                                      float* __restrict__ alpha,
                                                      float* __restrict__ out) {
  __shared__ float tmp[4];
  const int tid = threadIdx.x;
  float l[16];
  float m = -1e30f;
#pragma unroll
  for (int i = 0; i < 16; ++i) {
    l[i] = logits[i * 256 + tid];
    m = fmaxf(m, l[i]);
  }
#pragma unroll
  for (int o = 32; o > 0; o >>= 1) m = fmaxf(m, __shfl_xor(m, o));
  if ((tid & 63) == 0) tmp[tid >> 6] = m;
  __syncthreads();
  m = fmaxf(fmaxf(tmp[0], tmp[1]), fmaxf(tmp[2], tmp[3]));
  __syncthreads();
  float e[16];
  float s = 0.f;
#pragma unroll
  for (int i = 0; i < 16; ++i) {
    e[i] = expf(l[i] - m);
    s += e[i];
  }
#pragma unroll
  for (int o = 32; o > 0; o >>= 1) s += __shfl_xor(s, o);
  if ((tid & 63) == 0) tmp[tid >> 6] = s;
  __syncthreads();
  s = tmp[0] + tmp[1] + tmp[2] + tmp[3];
  const float inv = 1.f / s;
#pragma unroll
  for (int i = 0; i < 16; ++i) alpha[i * 256 + tid] = e[i] * inv;
  out[tid] = 0.f;
  out[256 + tid] = 0.f;
}

// ---------------------------------------------------------------------------
// out[j] = sum_t alpha[t] * hs[t][j].  128 WGs: 2 j-halves x 64 t-chunks.
// ---------------------------------------------------------------------------
__global__ __launch_bounds__(256) void wsum_kernel(const float* __restrict__ alpha,
                                                   const float* __restrict__ hs,
                                                   float* __restrict__ out) {
  const int tid = threadIdx.x;
  const int jblk = (blockIdx.x & 1) * 256;
  const int tc = blockIdx.x >> 1;
  float acc = 0.f;
  for (int tt = 0; tt < 64; ++tt) {
    const int t = tc * 64 + tt;
    acc += alpha[t] * hs[(size_t)t * HD + jblk + tid];
  }
  atomicAdd(&out[jblk + tid], acc);
}

extern "C" void kernel_launch(void* const* d_in, const int* in_sizes, int n_in,
                              void* d_out, int out_size, void* d_ws, size_t ws_size,
                              hipStream_t stream) {
  const float* H     = (const float*)d_in[0];
  // d_in[1] = TE, unused by the reference
  const float* X_emb = (const float*)d_in[2];
  const float* W_ih  = (const float*)d_in[3];
  const float* W_hh  = (const float*)d_in[4];
  const float* b_ih  = (const float*)d_in[5];
  const float* b_hh  = (const float*)d_in[6];
  const float* w_att = (const float*)d_in[7];
  float* out = (float*)d_out;

  char* ws = (char*)d_ws;
  float* visit  = (float*)(ws + 0);          //  8 MB: 4096x512
  float* gi     = (float*)(ws + 8388608);    // 25 MB: 4096x1536
  float* hs     = (float*)(ws + 33554432);   //  8 MB: 4096x512
  float* logits = (float*)(ws + 41943040);   // 16 KB: 4096
  float* alpha  = (float*)(ws + 42205184);   // 16 KB
  int*   ctrl   = (int*)(ws + 42221568);     // [0..7] per-XCD counters, [8] winner

  // sentinel-fill hs (0xFFFFFFFF = -NaN, unreachable from finite GRU math)
  hipMemsetAsync(hs, 0xFF, (size_t)T_STEPS * HD * sizeof(float), stream);
  hipMemsetAsync(ctrl, 0, 8 * sizeof(int), stream);
  hipMemsetAsync(ctrl + 8, 0xFF, sizeof(int), stream);  // winner = -1

  gemm1_kernel<<<dim3(64, 8), 256, 0, stream>>>(H, X_emb, visit);
  gemm2_kernel<<<dim3(64, 24), 256, 0, stream>>>(visit, W_ih, b_ih, gi);
  scan_kernel<<<256, 576, 0, stream>>>(gi, W_hh, b_hh, hs, ctrl);
  logits_kernel<<<64, 256, 0, stream>>>(hs, w_att, logits);
  softmax_kernel<<<1, 256, 0, stream>>>(logits, alpha, out);
  wsum_kernel<<<128, 256, 0, stream>>>(alpha, hs, out);
}

// Round 9
// 8363.851 us; speedup vs baseline: 1.8278x; 1.4318x over previous
//
#include <hip/hip_runtime.h>

#define T_STEPS 4096
#define HD 512
#define G3HD 1536
#define NCODES 4880
#define NWG 16
#define SENT 0xFFFFFFFFu

typedef __attribute__((ext_vector_type(2))) float v2f;
typedef unsigned long long u64;
typedef unsigned int u32;

#define AL64(P) __hip_atomic_load((P), __ATOMIC_RELAXED, __HIP_MEMORY_SCOPE_AGENT)

static __device__ inline bool ok64(u64 u) {
  return ((u32)u != SENT) & ((u32)(u >> 32) != SENT);
}

// ---------------------------------------------------------------------------
// GEMM1: visit[4096][512] = H^T (4096x4880) @ X_emb (4880x512)
// ---------------------------------------------------------------------------
__global__ __launch_bounds__(256) void gemm1_kernel(const float* __restrict__ H,
                                                    const float* __restrict__ X,
                                                    float* __restrict__ C) {
  __shared__ float As[16][68];
  __shared__ float Bs[16][68];
  const int m0 = blockIdx.x * 64;
  const int n0 = blockIdx.y * 64;
  const int tid = threadIdx.x;
  const int lk = tid >> 4;
  const int lm = (tid & 15) << 2;
  const int tm = (tid & 15) << 2;
  const int tn = (tid >> 4) << 2;
  float acc[4][4] = {};
  for (int k0 = 0; k0 < NCODES; k0 += 16) {
    float4 av = *(const float4*)(H + (size_t)(k0 + lk) * T_STEPS + m0 + lm);
    float4 bv = *(const float4*)(X + (size_t)(k0 + lk) * HD + n0 + lm);
    __syncthreads();
    *(float4*)(&As[lk][lm]) = av;
    *(float4*)(&Bs[lk][lm]) = bv;
    __syncthreads();
#pragma unroll
    for (int kk = 0; kk < 16; ++kk) {
      float4 a = *(const float4*)(&As[kk][tm]);
      float4 b = *(const float4*)(&Bs[kk][tn]);
      float ar[4] = {a.x, a.y, a.z, a.w};
      float br[4] = {b.x, b.y, b.z, b.w};
#pragma unroll
      for (int i = 0; i < 4; ++i)
#pragma unroll
        for (int j = 0; j < 4; ++j) acc[i][j] += ar[i] * br[j];
    }
  }
#pragma unroll
  for (int i = 0; i < 4; ++i) {
    float4 o = make_float4(acc[i][0], acc[i][1], acc[i][2], acc[i][3]);
    *(float4*)(C + (size_t)(m0 + tm + i) * HD + n0 + tn) = o;
  }
}

// ---------------------------------------------------------------------------
// GEMM2: gi[4096][1536] = visit (4096x512) @ W_ih^T (512x1536) + b_ih
// ---------------------------------------------------------------------------
__global__ __launch_bounds__(256) void gemm2_kernel(const float* __restrict__ A,
                                                    const float* __restrict__ B,
                                                    const float* __restrict__ bias,
                                                    float* __restrict__ Cout) {
  __shared__ float As[16][68];
  __shared__ float Bs[16][68];
  const int m0 = blockIdx.x * 64;
  const int n0 = blockIdx.y * 64;
  const int tid = threadIdx.x;
  const int lr = tid >> 2;
  const int lkq = (tid & 3) << 2;
  const int tm = (tid & 15) << 2;
  const int tn = (tid >> 4) << 2;
  float acc[4][4] = {};
  for (int k0 = 0; k0 < HD; k0 += 16) {
    float4 av = *(const float4*)(A + (size_t)(m0 + lr) * HD + k0 + lkq);
    float4 bv = *(const float4*)(B + (size_t)(n0 + lr) * HD + k0 + lkq);
    __syncthreads();
    As[lkq + 0][lr] = av.x; As[lkq + 1][lr] = av.y;
    As[lkq + 2][lr] = av.z; As[lkq + 3][lr] = av.w;
    Bs[lkq + 0][lr] = bv.x; Bs[lkq + 1][lr] = bv.y;
    Bs[lkq + 2][lr] = bv.z; Bs[lkq + 3][lr] = bv.w;
    __syncthreads();
#pragma unroll
    for (int kk = 0; kk < 16; ++kk) {
      float4 a = *(const float4*)(&As[kk][tm]);
      float4 b = *(const float4*)(&Bs[kk][tn]);
      float ar[4] = {a.x, a.y, a.z, a.w};
      float br[4] = {b.x, b.y, b.z, b.w};
#pragma unroll
      for (int i = 0; i < 4; ++i)
#pragma unroll
        for (int j = 0; j < 4; ++j) acc[i][j] += ar[i] * br[j];
    }
  }
  const float b0 = bias[n0 + tn + 0];
  const float b1 = bias[n0 + tn + 1];
  const float b2 = bias[n0 + tn + 2];
  const float b3 = bias[n0 + tn + 3];
#pragma unroll
  for (int i = 0; i < 4; ++i) {
    float4 o = make_float4(acc[i][0] + b0, acc[i][1] + b1, acc[i][2] + b2, acc[i][3] + b3);
    *(float4*)(Cout + (size_t)(m0 + tm + i) * G3HD + n0 + tn) = o;
  }
}

// ---------------------------------------------------------------------------
// Persistent GRU scan. R4-proven exchange (fp32, relaxed AGENT atomics,
// short-duty-cycle poll) + coalesced single-wave publish.
// 576 thr/WG, two barriers per step:
//   wave0 (tid<64): [poll h[t-1]: 4x u64 AGENT loads/lane vs 0xFFFFFFFF
//     sentinel -> scatter fp32 pairs to hT2] B1 [wait] B2 [lanes 0..31:
//     ONE wave-coalesced AGENT store of the WG's 32 hnew dwords (= 2 cache
//     lines, 2 MALL write transactions, zero wave-skew) then loop to poll].
//     Poll duty cycle is short (starts only after publish) -- R8's
//     continuous-spin contention is avoided.
//   compute (tid>=64): B1 [pk_fma matvec from reg-resident W_hh slice +
//     shfl_xor allreduce; gate lanes (kc<2) gates via native exp/rcp ->
//     s_hout LDS] B2.
// Race-free: hT2 written only in (B2,B1] by wave0, read only in (B1,B2] by
// compute; s_hout vice-versa. Barrier counts match across all waves.
// ---------------------------------------------------------------------------
__global__ __launch_bounds__(576, 1) void scan_kernel(const float* __restrict__ gi,
                                                      const float* __restrict__ W_hh,
                                                      const float* __restrict__ b_hh,
                                                      float* __restrict__ hs,
                                                      int* __restrict__ ctrl) {
  __shared__ int s_role;
  __shared__ v2f hT2[256];      // h[k] pairs: k=16*kc+2m at hT2[m*32+kc]
  __shared__ float s_hout[32];  // this WG's 32 hnew values for step t
  const int tid = threadIdx.x;

  if (tid == 0) {
    int xcd;
    asm volatile("s_getreg_b32 %0, hwreg(HW_REG_XCC_ID)" : "=s"(xcd));
    int role = -1;
    const int slot = atomicAdd(&ctrl[xcd], 1);
    if (slot < NWG) {
      if (slot == NWG - 1) atomicCAS(&ctrl[8], -1, xcd);
      int wnr;
      while ((wnr = __hip_atomic_load(&ctrl[8], __ATOMIC_RELAXED,
                                      __HIP_MEMORY_SCOPE_AGENT)) < 0) {
        __builtin_amdgcn_s_sleep(16);
      }
      if (wnr == xcd) role = slot;
    }
    s_role = role;
  }
  __syncthreads();
  const int g = s_role;
  if (g < 0) return;

  unsigned int* hs_u = (unsigned int*)hs;

  if (tid < 64) {
    // ------------------------- POLLER / PUBLISHER WAVE -------------------------
    const int ln = tid;
    for (int t = 0; t < T_STEPS; ++t) {
      if (t == 0) {
        const v2f z2 = (v2f)(0.f);
#pragma unroll
        for (int m = 0; m < 4; ++m) hT2[((ln & 1) * 4 + m) * 32 + (ln >> 1)] = z2;
      } else {
        const u64* p = (const u64*)(hs_u + (size_t)(t - 1) * HD) + ln * 4;
        u64 u[4];
        bool ok;
        do {
          ok = true;
#pragma unroll
          for (int m = 0; m < 4; ++m) u[m] = AL64(p + m);
#pragma unroll
          for (int m = 0; m < 4; ++m) ok &= ok64(u[m]);
        } while (!ok);
        const int base = (ln & 1) * 4;  // k = ln*8+2m -> pair (ln&1)*4+m, col ln>>1
        const int col = ln >> 1;
#pragma unroll
        for (int m = 0; m < 4; ++m) {
          v2f pv;
          pv.x = __uint_as_float((u32)u[m]);
          pv.y = __uint_as_float((u32)(u[m] >> 32));
          hT2[(base + m) * 32 + col] = pv;
        }
      }
      __syncthreads();  // B1: hT2 = h[t-1] released to compute waves
      __syncthreads();  // B2: s_hout = h[t] ready
      if (ln < 32) {    // ONE coalesced publish: 32 contiguous dwords, 2 lines
        const u32 bits = __float_as_uint(s_hout[ln]);
        __hip_atomic_store(hs_u + (size_t)t * HD + g * 32 + ln, bits,
                           __ATOMIC_RELAXED, __HIP_MEMORY_SCOPE_AGENT);
      }
    }
    return;
  }

  // ------------------------- COMPUTE THREADS -------------------------
  const int ct = tid - 64;
  const int rg = ct >> 5;   // 0..15: owns local elems j0=2rg, j1=2rg+1
  const int kc = ct & 31;   // k-chunk: 16 k (8 pairs) per lane

  // 6 rows: r=0..2 -> gates r/z/n of j0; r=3..5 -> gates of j1
  v2f w2[6][8];
#pragma unroll
  for (int r = 0; r < 6; ++r) {
    const int jl = 2 * rg + (r >= 3);
    const int grow = (r % 3) * HD + g * 32 + jl;
    const v2f* wv = (const v2f*)(W_hh + (size_t)grow * HD + kc * 16);
#pragma unroll
    for (int m = 0; m < 8; ++m) w2[r][m] = wv[m];
  }

  float bh0 = 0.f, bh1 = 0.f, bh2 = 0.f;
  const int jloc = 2 * rg + kc;  // valid for kc<2
  if (kc < 2) {
    bh0 = b_hh[0 * HD + g * 32 + jloc];
    bh1 = b_hh[1 * HD + g * 32 + jloc];
    bh2 = b_hh[2 * HD + g * 32 + jloc];
  }

  float gir = 0.f, giz = 0.f, gin = 0.f;
  if (kc < 2) {
    const float* gp = gi + g * 32 + jloc;
    gir = gp[0];
    giz = gp[HD];
    gin = gp[2 * HD];
  }

  for (int t = 0; t < T_STEPS; ++t) {
    __syncthreads();  // B1: hT2 = h[t-1] ready

    // prefetch next step's gi (hidden behind matvec)
    float gir_n = gir, giz_n = giz, gin_n = gin;
    if (kc < 2 && t + 1 < T_STEPS) {
      const float* gp = gi + (size_t)(t + 1) * G3HD + g * 32 + jloc;
      gir_n = gp[0];
      giz_n = gp[HD];
      gin_n = gp[2 * HD];
    }

    v2f acc[6];
#pragma unroll
    for (int r = 0; r < 6; ++r) acc[r] = (v2f)(0.f);
#pragma unroll
    for (int m = 0; m < 8; ++m) {
      const v2f hv = hT2[m * 32 + kc];
#pragma unroll
      for (int r = 0; r < 6; ++r) acc[r] = __builtin_elementwise_fma(w2[r][m], hv, acc[r]);
    }
    float s[6];
#pragma unroll
    for (int r = 0; r < 6; ++r) s[r] = acc[r].x + acc[r].y;
#pragma unroll
    for (int mask = 1; mask <= 16; mask <<= 1) {
#pragma unroll
      for (int r = 0; r < 6; ++r) s[r] += __shfl_xor(s[r], mask);
    }

    if (kc < 2) {
      const float sr = ((kc == 0) ? s[0] : s[3]) + bh0;
      const float sz = ((kc == 0) ? s[1] : s[4]) + bh1;
      const float sn = ((kc == 0) ? s[2] : s[5]) + bh2;
      const float r = __builtin_amdgcn_rcpf(1.f + __expf(-(gir + sr)));
      const float z = __builtin_amdgcn_rcpf(1.f + __expf(-(giz + sz)));
      const float y = gin + r * sn;
      const float n = 1.f - 2.f * __builtin_amdgcn_rcpf(__expf(2.f * y) + 1.f);
      const int kg = g * 32 + jloc;
      const float hprev = ((const float*)hT2)[((kg & 15) >> 1) * 64 + (kg >> 4) * 2 + (kg & 1)];
      const float hnew = n + z * (hprev - n);
      s_hout[jloc] = hnew;
    }
    __syncthreads();  // B2: s_hout ready for the publisher wave
    gir = gir_n; giz = giz_n; gin = gin_n;
  }
}

// ---------------------------------------------------------------------------
// logits[t] = dot(hs[t], w_att).  64 WGs x 4 waves; one wave per 16 t-rows.
// ---------------------------------------------------------------------------
__global__ __launch_bounds__(256) void logits_kernel(const float* __restrict__ hs,
                                                     const float* __restrict__ w_att,
                                                     float* __restrict__ logits) {
  const int lane = threadIdx.x & 63;
  const int wv = threadIdx.x >> 6;  // 0..3
  float4 wa0 = *(const float4*)(w_att + lane * 8);
  float4 wa1 = *(const float4*)(w_att + lane * 8 + 4);
  const int t0 = blockIdx.x * 64 + wv * 16;
  for (int i = 0; i < 16; ++i) {
    const int t = t0 + i;
    const float* hp = hs + (size_t)t * HD + lane * 8;
    float4 h0 = *(const float4*)hp;
    float4 h1 = *(const float4*)(hp + 4);
    float s = h0.x * wa0.x + h0.y * wa0.y + h0.z * wa0.z + h0.w * wa0.w +
              h1.x * wa1.x + h1.y * wa1.y + h1.z * wa1.z + h1.w * wa1.w;
#pragma unroll
    for (int o = 1; o <= 32; o <<= 1) s += __shfl_xor(s, o);
    if (lane == 0) logits[t] = s;
  }
}

// ---------------------------------------------------------------------------
// Softmax over 4096 logits, write alpha; zero out.
// ---------------------------------------------------------------------------
__global__ __launch_bounds__(256) void softmax_kernel(const float* __restrict__ logits,
                                                      float* __restrict__ alpha,
                                                      float* __restrict__ out) {
  __shared__ float tmp[4];
  const int tid = threadIdx.x;
  float l[16];
  float m = -1e30f;
#pragma unroll
  for (int i = 0; i < 16; ++i) {
    l[i] = logits[i * 256 + tid];
    m = fmaxf(m, l[i]);
  }
#pragma unroll
  for (int o = 32; o > 0; o >>= 1) m = fmaxf(m, __shfl_xor(m, o));
  if ((tid & 63) == 0) tmp[tid >> 6] = m;
  __syncthreads();
  m = fmaxf(fmaxf(tmp[0], tmp[1]), fmaxf(tmp[2], tmp[3]));
  __syncthreads();
  float e[16];
  float s = 0.f;
#pragma unroll
  for (int i = 0; i < 16; ++i) {
    e[i] = expf(l[i] - m);
    s += e[i];
  }
#pragma unroll
  for (int o = 32; o > 0; o >>= 1) s += __shfl_xor(s, o);
  if ((tid & 63) == 0) tmp[tid >> 6] = s;
  __syncthreads();
  s = tmp[0] + tmp[1] + tmp[2] + tmp[3];
  const float inv = 1.f / s;
#pragma unroll
  for (int i = 0; i < 16; ++i) alpha[i * 256 + tid] = e[i] * inv;
  out[tid] = 0.f;
  out[256 + tid] = 0.f;
}

// ---------------------------------------------------------------------------
// out[j] = sum_t alpha[t] * hs[t][j].  128 WGs: 2 j-halves x 64 t-chunks.
// ---------------------------------------------------------------------------
__global__ __launch_bounds__(256) void wsum_kernel(const float* __restrict__ alpha,
                                                   const float* __restrict__ hs,
                                                   float* __restrict__ out) {
  const int tid = threadIdx.x;
  const int jblk = (blockIdx.x & 1) * 256;
  const int tc = blockIdx.x >> 1;
  float acc = 0.f;
  for (int tt = 0; tt < 64; ++tt) {
    const int t = tc * 64 + tt;
    acc += alpha[t] * hs[(size_t)t * HD + jblk + tid];
  }
  atomicAdd(&out[jblk + tid], acc);
}

extern "C" void kernel_launch(void* const* d_in, const int* in_sizes, int n_in,
                              void* d_out, int out_size, void* d_ws, size_t ws_size,
                              hipStream_t stream) {
  const float* H     = (const float*)d_in[0];
  // d_in[1] = TE, unused by the reference
  const float* X_emb = (const float*)d_in[2];
  const float* W_ih  = (const float*)d_in[3];
  const float* W_hh  = (const float*)d_in[4];
  const float* b_ih  = (const float*)d_in[5];
  const float* b_hh  = (const float*)d_in[6];
  const float* w_att = (const float*)d_in[7];
  float* out = (float*)d_out;

  char* ws = (char*)d_ws;
  float* visit  = (float*)(ws + 0);          //  8 MB: 4096x512
  float* gi     = (float*)(ws + 8388608);    // 25 MB: 4096x1536
  float* hs     = (float*)(ws + 33554432);   //  8 MB: 4096x512
  float* logits = (float*)(ws + 41943040);   // 16 KB: 4096
  float* alpha  = (float*)(ws + 42205184);   // 16 KB
  int*   ctrl   = (int*)(ws + 42221568);     // [0..7] per-XCD counters, [8] winner

  // sentinel-fill hs (0xFFFFFFFF = -NaN, unreachable from finite GRU math)
  hipMemsetAsync(hs, 0xFF, (size_t)T_STEPS * HD * sizeof(float), stream);
  hipMemsetAsync(ctrl, 0, 8 * sizeof(int), stream);
  hipMemsetAsync(ctrl + 8, 0xFF, sizeof(int), stream);  // winner = -1

  gemm1_kernel<<<dim3(64, 8), 256, 0, stream>>>(H, X_emb, visit);
  gemm2_kernel<<<dim3(64, 24), 256, 0, stream>>>(visit, W_ih, b_ih, gi);
  scan_kernel<<<256, 576, 0, stream>>>(gi, W_hh, b_hh, hs, ctrl);
  logits_kernel<<<64, 256, 0, stream>>>(hs, w_att, logits);
  softmax_kernel<<<1, 256, 0, stream>>>(logits, alpha, out);
  wsum_kernel<<<128, 256, 0, stream>>>(alpha, hs, out);
}